// Round 1
// baseline (514.369 us; speedup 1.0000x reference)
//
#include <hip/hip_runtime.h>

// SphericalSmearing: real spherical harmonics, MAX_N=16, 500k points.
// out shape (N, 256) fp32 row-major:
//   cols [0,16)    : harm_re for m==0, n=0..15
//   cols [16,136)  : harm_re for m>=1, ordered (n asc, m=1..n), idx = n(n-1)/2 + (m-1)
//   cols [136,256) : harm_im, same ordering, = re col + 120
//
// Strategy: block=64 threads, 64 points/block. Two passes over column halves
// (recompute recurrence, emit sites compile-time gated). Stage into LDS with
// in-row swizzle slot=(c>>2)+((c&3)<<5) and row pad 129 -> conflict-free LDS
// writes AND reads. Flush as dense float4 stores (coalesced, 1KB/inst/wave).

#define NMAX   16
#define BLOCK  64
#define HALF   128
#define PAD    129   // floats per LDS row (128 data + 1 pad)

// ---- compile-time coefficient table ----
constexpr double cfact(int k) { double r = 1.0; for (int i = 2; i <= k; ++i) r *= (double)i; return r; }
constexpr double csqrt_(double x) {
    double g = x > 1.0 ? x : 1.0;
    for (int i = 0; i < 120; ++i) g = 0.5 * (g + x / g);
    return g;
}
constexpr double PI_ = 3.14159265358979323846;

struct CoefTab { float c[NMAX][NMAX]; };
constexpr CoefTab make_coef() {
    CoefTab t{};
    for (int n = 0; n < NMAX; ++n)
        for (int m = 0; m <= n; ++m)
            t.c[n][m] = (float)csqrt_(((2.0 * n + 1.0) / (4.0 * PI_)) * cfact(n - m) / cfact(n + m));
    return t;
}
constexpr CoefTab COEF = make_coef();

// ---- staging helpers (fold to single ds_write or nothing after unroll) ----
template <int PASS>
__device__ __forceinline__ void stage(float* rowPtr, int col, float v) {
    constexpr int lo = PASS * HALF;
    if (col >= lo && col < lo + HALF) {
        int c = col - lo;
        rowPtr[(c >> 2) + ((c & 3) << 5)] = v;
    }
}

template <int PASS>
__device__ __forceinline__ void emit(float* rowPtr, int n, int m, float p, float cm, float sm) {
    float v = COEF.c[n][m] * p;
    if (m == 0) {
        stage<PASS>(rowPtr, n, v);
    } else {
        int col = 16 + (n * (n - 1)) / 2 + (m - 1);
        stage<PASS>(rowPtr, col, v * cm);         // re
        stage<PASS>(rowPtr, col + 120, v * sm);   // im
    }
}

template <int PASS>
__device__ __forceinline__ void compute_stage(float ct, float st, float c1, float s1, float* rowPtr) {
    float pmm = 1.0f;           // P[m][m]
    float cm = 1.0f, sm = 0.0f; // cos(m*phi), sin(m*phi)
#pragma unroll
    for (int m = 0; m < NMAX; ++m) {
        emit<PASS>(rowPtr, m, m, pmm, cm, sm);
        float pn2 = pmm;
        if (m < NMAX - 1) {
            float pn1 = (float)(2 * m + 1) * ct * pmm;
            emit<PASS>(rowPtr, m + 1, m, pn1, cm, sm);
#pragma unroll
            for (int n = m + 2; n < NMAX; ++n) {
                float pn = ((float)(2 * n - 1) * ct * pn1 - (float)(n + m - 1) * pn2)
                           * (1.0f / (float)(n - m));
                emit<PASS>(rowPtr, n, m, pn, cm, sm);
                pn2 = pn1;
                pn1 = pn;
            }
        }
        pmm = -(float)(2 * m + 1) * st * pmm;     // P[m+1][m+1]
        float cn = cm * c1 - sm * s1;             // angle-addition
        sm = sm * c1 + cm * s1;
        cm = cn;
    }
}

template <int PASS>
__device__ __forceinline__ void flush(const float* tile, float* out, long long rowBase, int npts, int t) {
#pragma unroll
    for (int k = 0; k < 32; ++k) {
        int flat4 = k * 64 + t;
        int row   = flat4 >> 5;   // 32 float4 per half-row
        int c4    = flat4 & 31;
        long long grow = rowBase + row;
        if (grow < (long long)npts) {
            const float* p = tile + row * PAD + c4;
            float4 v = make_float4(p[0], p[32], p[64], p[96]);
            *reinterpret_cast<float4*>(out + grow * 256 + PASS * HALF + 4 * c4) = v;
        }
    }
}

__global__ __launch_bounds__(BLOCK)
void sph_harm_kernel(const float* __restrict__ xyz, float* __restrict__ out, int npts) {
    __shared__ float tile[BLOCK * PAD];
    const int t = threadIdx.x;
    const long long rowBase = (long long)blockIdx.x * BLOCK;
    long long pt = rowBase + t;
    long long cpt = pt < npts ? pt : (long long)npts - 1;

    float x = xyz[3 * cpt + 0];
    float y = xyz[3 * cpt + 1];
    float z = xyz[3 * cpt + 2];

    float r2 = x * x + y * y + z * z;
    float r  = sqrtf(r2);
    float ct = z / r;
    float st = sqrtf(fmaxf(1.0f - ct * ct, 0.0f));

    float rho2 = x * x + y * y;
    float c1, s1;
    if (rho2 > 0.0f) {
        float rinv = 1.0f / sqrtf(rho2);
        c1 = x * rinv;
        s1 = y * rinv;
    } else {
        c1 = 1.0f;  // theta = atan2(-0,-0)+pi -> 0
        s1 = 0.0f;
    }

    float* rowPtr = tile + t * PAD;

    compute_stage<0>(ct, st, c1, s1, rowPtr);
    __syncthreads();
    flush<0>(tile, out, rowBase, npts, t);
    __syncthreads();
    compute_stage<1>(ct, st, c1, s1, rowPtr);
    __syncthreads();
    flush<1>(tile, out, rowBase, npts, t);
}

extern "C" void kernel_launch(void* const* d_in, const int* in_sizes, int n_in,
                              void* d_out, int out_size, void* d_ws, size_t ws_size,
                              hipStream_t stream) {
    const float* xyz = (const float*)d_in[0];
    float* out = (float*)d_out;
    int npts = in_sizes[0] / 3;
    int blocks = (npts + BLOCK - 1) / BLOCK;
    hipLaunchKernelGGL(sph_harm_kernel, dim3(blocks), dim3(BLOCK), 0, stream,
                       xyz, out, npts);
}